// Round 3
// baseline (2349.484 us; speedup 1.0000x reference)
//
#include <hip/hip_runtime.h>
#include <math.h>

#define BKT_SHIFT 8
#define BKT_NODES 256

// ---- pass 1: per-node degree (global atomics) + per-bucket histogram (LDS) ----
__global__ __launch_bounds__(256) void k_count_hist(const int* __restrict__ dst,
                                                    int* __restrict__ cnt,
                                                    int* __restrict__ bcnt, int E, int NB) {
    __shared__ int lh[1024];
    for (int i = threadIdx.x; i < NB; i += 256) lh[i] = 0;
    __syncthreads();
    int base = blockIdx.x * 4096;
#pragma unroll
    for (int k = 0; k < 16; ++k) {
        int i = base + k * 256 + threadIdx.x;
        if (i < E) {
            int d = dst[i];
            atomicAdd(&cnt[d], 1);
            atomicAdd(&lh[d >> BKT_SHIFT], 1);
        }
    }
    __syncthreads();
    for (int i = threadIdx.x; i < NB; i += 256)
        if (lh[i]) atomicAdd(&bcnt[i], lh[i]);
}

__global__ __launch_bounds__(256) void k_dinv(const int* __restrict__ cnt,
                                              float* __restrict__ dinv, int n) {
    int i = blockIdx.x * 256 + threadIdx.x;
    if (i < n) dinv[i] = rsqrtf((float)cnt[i] + 1.0f);  // +1 = self-loop
}

// ---- exclusive scan over NB buckets (single block, chunks of 512) ----
__global__ __launch_bounds__(512) void k_bscan(const int* __restrict__ bc,
                                               int* __restrict__ boff,
                                               int* __restrict__ bcur, int NB, int E) {
    __shared__ int s[512];
    __shared__ int carry;
    if (threadIdx.x == 0) carry = 0;
    __syncthreads();
    for (int base = 0; base < NB; base += 512) {
        int i = base + threadIdx.x;
        int v = (i < NB) ? bc[i] : 0;
        s[threadIdx.x] = v;
        __syncthreads();
        for (int off = 1; off < 512; off <<= 1) {
            int t = (threadIdx.x >= off) ? s[threadIdx.x - off] : 0;
            __syncthreads();
            s[threadIdx.x] += t;
            __syncthreads();
        }
        if (i < NB) {
            int ex = carry + s[threadIdx.x] - v;
            boff[i] = ex;
            bcur[i] = ex;
        }
        __syncthreads();
        if (threadIdx.x == 0) carry += s[511];
        __syncthreads();
    }
    if (threadIdx.x == 0) boff[NB] = E;
}

// ---- pass 2: partition edges into bucket-ordered packed records ----
// record = ((d & 255) << 24) | src   (src < 2^24)
__global__ __launch_bounds__(256) void k_part(const int* __restrict__ src,
                                              const int* __restrict__ dst,
                                              int* __restrict__ bcur,
                                              int* __restrict__ ebuf, int E, int NB) {
    __shared__ int dstash[8192];
    __shared__ int lh[1024];
    for (int i = threadIdx.x; i < NB; i += 256) lh[i] = 0;
    __syncthreads();
    int base = blockIdx.x * 8192;
#pragma unroll
    for (int k = 0; k < 32; ++k) {
        int idx = k * 256 + threadIdx.x;
        int i = base + idx;
        if (i < E) {
            int d = dst[i];
            dstash[idx] = d;
            atomicAdd(&lh[d >> BKT_SHIFT], 1);
        }
    }
    __syncthreads();
    // reserve global ranges: one atomic per (bucket, block)
    for (int t = threadIdx.x; t < NB; t += 256) {
        int c = lh[t];
        lh[t] = c ? atomicAdd(&bcur[t], c) : 0;
    }
    __syncthreads();
#pragma unroll
    for (int k = 0; k < 32; ++k) {
        int idx = k * 256 + threadIdx.x;
        int i = base + idx;
        if (i < E) {
            int d = dstash[idx];
            int pos = atomicAdd(&lh[d >> BKT_SHIFT], 1);
            ebuf[pos] = ((d & (BKT_NODES - 1)) << 24) | src[i];
        }
    }
}

// ---- h1 = x @ W1 (8 -> 64) ----
__global__ __launch_bounds__(256) void k_gemm1(const float* __restrict__ x, const float* __restrict__ W1,
                                               float* __restrict__ h1, int n) {
    __shared__ float w[512];
    for (int i = threadIdx.x; i < 512; i += 256) w[i] = W1[i];
    __syncthreads();
    int t = blockIdx.x * 256 + threadIdx.x;
    int node = t >> 6, j = t & 63;
    if (node >= n) return;
    float s = 0.f;
#pragma unroll
    for (int k = 0; k < 8; ++k) s += x[node * 8 + k] * w[k * 64 + j];
    h1[t] = s;
}

// ---- bucket-direct aggregation, 64 feats, LDS accumulator, fused bias+ELU ----
__global__ __launch_bounds__(512) void k_agg1(const int* __restrict__ boff, const int* __restrict__ ebuf,
                                              const float* __restrict__ dinv, const float* __restrict__ h,
                                              const float* __restrict__ bias, float* __restrict__ g, int n) {
    __shared__ float acc[BKT_NODES * 64];  // 64 KB
    for (int i = threadIdx.x; i < BKT_NODES * 64; i += 512) acc[i] = 0.f;
    __syncthreads();
    int b = blockIdx.x;
    int start = boff[b], end = boff[b + 1];
    int wid = threadIdx.x >> 6, lane = threadIdx.x & 63;
    for (int i = start + wid * 4; i < end; i += 32) {
#pragma unroll
        for (int u = 0; u < 4; ++u) {
            int ii = i + u;
            if (ii < end) {
                int v = ebuf[ii];
                int s = v & 0xFFFFFF;
                int db = ((unsigned)v) >> 24;
                float dv = dinv[s];
                atomicAdd(&acc[db * 64 + lane], h[(size_t)s * 64 + lane] * dv);
            }
        }
    }
    __syncthreads();
    int nbase = b << BKT_SHIFT;
    for (int idx = threadIdx.x; idx < BKT_NODES * 64; idx += 512) {
        int r = idx >> 6, j = idx & 63;
        int node = nbase + r;
        if (node < n) {
            float dv = dinv[node];
            float val = dv * (acc[idx] + dv * h[(size_t)node * 64 + j]) + bias[j];
            g[(size_t)node * 64 + j] = val > 0.f ? val : expm1f(val);
        }
    }
}

// ---- bucket-direct aggregation, 32 feats (2 edges per wave) ----
__global__ __launch_bounds__(512) void k_agg2(const int* __restrict__ boff, const int* __restrict__ ebuf,
                                              const float* __restrict__ dinv, const float* __restrict__ h,
                                              const float* __restrict__ bias, float* __restrict__ g, int n) {
    __shared__ float acc[BKT_NODES * 32];  // 32 KB
    for (int i = threadIdx.x; i < BKT_NODES * 32; i += 512) acc[i] = 0.f;
    __syncthreads();
    int b = blockIdx.x;
    int start = boff[b], end = boff[b + 1];
    int wid = threadIdx.x >> 6, half = (threadIdx.x >> 5) & 1, j = threadIdx.x & 31;
    for (int i = start + wid * 8; i < end; i += 64) {
#pragma unroll
        for (int u = 0; u < 4; ++u) {
            int ii = i + u * 2 + half;
            if (ii < end) {
                int v = ebuf[ii];
                int s = v & 0xFFFFFF;
                int db = ((unsigned)v) >> 24;
                float dv = dinv[s];
                atomicAdd(&acc[db * 32 + j], h[(size_t)s * 32 + j] * dv);
            }
        }
    }
    __syncthreads();
    int nbase = b << BKT_SHIFT;
    for (int idx = threadIdx.x; idx < BKT_NODES * 32; idx += 512) {
        int r = idx >> 5, j2 = idx & 31;
        int node = nbase + r;
        if (node < n) {
            float dv = dinv[node];
            float val = dv * (acc[idx] + dv * h[(size_t)node * 32 + j2]) + bias[j2];
            g[(size_t)node * 32 + j2] = val > 0.f ? val : expm1f(val);
        }
    }
}

// ---- h2 = g1 @ W2 (64 -> 32) ----
__global__ __launch_bounds__(256) void k_gemm2(const float* __restrict__ g1, const float* __restrict__ W2,
                                               float* __restrict__ h2, int n) {
    __shared__ float w[2048];
    __shared__ float xs[512];
    for (int i = threadIdx.x; i < 2048; i += 256) w[i] = W2[i];
    int nb = blockIdx.x * 8;
    for (int i = threadIdx.x; i < 512; i += 256) {
        int r = i >> 6, c = i & 63;
        int node = nb + r;
        xs[i] = (node < n) ? g1[(size_t)node * 64 + c] : 0.f;
    }
    __syncthreads();
    int node = nb + (threadIdx.x >> 5);
    int j = threadIdx.x & 31;
    if (node >= n) return;
    const float* xr = &xs[(threadIdx.x >> 5) << 6];
    float s = 0.f;
#pragma unroll
    for (int k = 0; k < 64; ++k) s += xr[k] * w[k * 32 + j];
    h2[(size_t)node * 32 + j] = s;
}

// ---- conv1d(32->16,k=3) + relu + fc(16->22) ----
__global__ __launch_bounds__(256) void k_head(const float* __restrict__ g2, const float* __restrict__ cw,
                                              const float* __restrict__ cb, const float* __restrict__ fw,
                                              const float* __restrict__ fb, float* __restrict__ out,
                                              int nrows) {
    __shared__ float scw[1536], sfw[352], scb[16], sfb[22];
    for (int i = threadIdx.x; i < 1536; i += 256) scw[i] = cw[i];
    for (int i = threadIdx.x; i < 352; i += 256) sfw[i] = fw[i];
    if (threadIdx.x < 16) scb[threadIdx.x] = cb[threadIdx.x];
    if (threadIdx.x < 22) sfb[threadIdx.x] = fb[threadIdx.x];
    __syncthreads();
    int l = blockIdx.x * 256 + threadIdx.x;
    if (l >= nrows) return;
    float xv[96];
    const float4* g4 = reinterpret_cast<const float4*>(g2);
#pragma unroll
    for (int k = 0; k < 3; ++k)
#pragma unroll
        for (int q = 0; q < 8; ++q) {
            float4 v = g4[(size_t)(l + k) * 8 + q];
            xv[k * 32 + q * 4 + 0] = v.x;
            xv[k * 32 + q * 4 + 1] = v.y;
            xv[k * 32 + q * 4 + 2] = v.z;
            xv[k * 32 + q * 4 + 3] = v.w;
        }
    float y[16];
#pragma unroll
    for (int co = 0; co < 16; ++co) {
        float s = scb[co];
#pragma unroll
        for (int ci = 0; ci < 32; ++ci) {
#pragma unroll
            for (int k = 0; k < 3; ++k)
                s += xv[k * 32 + ci] * scw[co * 96 + ci * 3 + k];
        }
        y[co] = s > 0.f ? s : 0.f;
    }
#pragma unroll
    for (int t = 0; t < 22; ++t) {
        float s = sfb[t];
#pragma unroll
        for (int co = 0; co < 16; ++co) s += y[co] * sfw[co * 22 + t];
        out[(size_t)l * 22 + t] = s;
    }
}

extern "C" void kernel_launch(void* const* d_in, const int* in_sizes, int n_in,
                              void* d_out, int out_size, void* d_ws, size_t ws_size,
                              hipStream_t stream) {
    const float* x  = (const float*)d_in[0];
    const int*   ei = (const int*)d_in[1];   // int32 (JAX x64 disabled)
    const float* W1 = (const float*)d_in[2];
    const float* b1 = (const float*)d_in[3];
    const float* W2 = (const float*)d_in[4];
    const float* b2 = (const float*)d_in[5];
    const float* cw = (const float*)d_in[6];
    const float* cb = (const float*)d_in[7];
    const float* fw = (const float*)d_in[8];
    const float* fb = (const float*)d_in[9];
    float* out = (float*)d_out;

    int N = in_sizes[0] / 8;       // 100000
    int E = in_sizes[1] / 2;       // 3200000
    const int* src = ei;
    const int* dst = ei + E;
    int NB = (N + BKT_NODES - 1) >> BKT_SHIFT;  // 391

    auto align256 = [](size_t v) { return (v + 255) & ~(size_t)255; };
    float* ws = (float*)d_ws;
    size_t o = 0;
    int* cnt = (int*)(ws + o);   o += align256(N);
    int* bcnt = (int*)(ws + o);  o += align256(NB);
    float* dinv = ws + o;        o += align256(N);
    int* boff = (int*)(ws + o);  o += align256(NB + 1);
    int* bcur = (int*)(ws + o);  o += align256(NB);
    int* ebuf = (int*)(ws + o);  o += align256(E);
    float* A = ws + o;           o += (size_t)N * 64;   // h1, then h2
    float* B = ws + o;           o += (size_t)N * 64;   // g1, then g2

    hipMemsetAsync(cnt, 0, (size_t)N * sizeof(int), stream);
    hipMemsetAsync(bcnt, 0, (size_t)NB * sizeof(int), stream);
    k_count_hist<<<(E + 4095) / 4096, 256, 0, stream>>>(dst, cnt, bcnt, E, NB);
    k_dinv<<<(N + 255) / 256, 256, 0, stream>>>(cnt, dinv, N);
    k_bscan<<<1, 512, 0, stream>>>(bcnt, boff, bcur, NB, E);
    k_part<<<(E + 8191) / 8192, 256, 0, stream>>>(src, dst, bcur, ebuf, E, NB);

    float* h1 = A;
    float* g1 = B;
    k_gemm1<<<(int)(((size_t)N * 64 + 255) / 256), 256, 0, stream>>>(x, W1, h1, N);
    k_agg1<<<NB, 512, 0, stream>>>(boff, ebuf, dinv, h1, b1, g1, N);

    float* h2 = A;
    float* g2 = B;
    k_gemm2<<<(N + 7) / 8, 256, 0, stream>>>(g1, W2, h2, N);
    k_agg2<<<NB, 512, 0, stream>>>(boff, ebuf, dinv, h2, b2, g2, N);

    k_head<<<(N - 2 + 255) / 256, 256, 0, stream>>>(g2, cw, cb, fw, fb, out, N - 2);
}

// Round 4
// 378.519 us; speedup vs baseline: 6.2071x; 6.2071x over previous
//
#include <hip/hip_runtime.h>
#include <math.h>

#define BKT_SHIFT 8
#define BKT_NODES 256

// ---- pass 1: per-bucket histogram only (LDS + one global atomic per bucket/block) ----
__global__ __launch_bounds__(256) void k_hist(const int* __restrict__ dst,
                                              int* __restrict__ bcnt, int E, int NB) {
    __shared__ int lh[512];
    for (int i = threadIdx.x; i < NB; i += 256) lh[i] = 0;
    __syncthreads();
    int base = blockIdx.x * 4096;
#pragma unroll
    for (int k = 0; k < 16; ++k) {
        int i = base + k * 256 + threadIdx.x;
        if (i < E) atomicAdd(&lh[dst[i] >> BKT_SHIFT], 1);
    }
    __syncthreads();
    for (int i = threadIdx.x; i < NB; i += 256)
        if (lh[i]) atomicAdd(&bcnt[i], lh[i]);
}

// ---- exclusive scan over NB buckets (single block) ----
__global__ __launch_bounds__(512) void k_bscan(const int* __restrict__ bc,
                                               int* __restrict__ boff,
                                               int* __restrict__ bcur, int NB, int E) {
    __shared__ int s[512];
    __shared__ int carry;
    if (threadIdx.x == 0) carry = 0;
    __syncthreads();
    for (int base = 0; base < NB; base += 512) {
        int i = base + threadIdx.x;
        int v = (i < NB) ? bc[i] : 0;
        s[threadIdx.x] = v;
        __syncthreads();
        for (int off = 1; off < 512; off <<= 1) {
            int t = (threadIdx.x >= off) ? s[threadIdx.x - off] : 0;
            __syncthreads();
            s[threadIdx.x] += t;
            __syncthreads();
        }
        if (i < NB) {
            int ex = carry + s[threadIdx.x] - v;
            boff[i] = ex;
            bcur[i] = ex;
        }
        __syncthreads();
        if (threadIdx.x == 0) carry += s[511];
        __syncthreads();
    }
    if (threadIdx.x == 0) boff[NB] = E;
}

// ---- pass 2: partition edges into bucket ranges; record = (d&255)<<24 | src ----
__global__ __launch_bounds__(256) void k_part(const int* __restrict__ src,
                                              const int* __restrict__ dst,
                                              int* __restrict__ bcur,
                                              int* __restrict__ ebuf, int E, int NB) {
    __shared__ int dstash[8192];
    __shared__ int lh[512];
    for (int i = threadIdx.x; i < NB; i += 256) lh[i] = 0;
    __syncthreads();
    int base = blockIdx.x * 8192;
#pragma unroll
    for (int k = 0; k < 32; ++k) {
        int idx = k * 256 + threadIdx.x;
        int i = base + idx;
        if (i < E) {
            int d = dst[i];
            dstash[idx] = d;
            atomicAdd(&lh[d >> BKT_SHIFT], 1);
        }
    }
    __syncthreads();
    for (int t = threadIdx.x; t < NB; t += 256) {
        int c = lh[t];
        lh[t] = c ? atomicAdd(&bcur[t], c) : 0;
    }
    __syncthreads();
#pragma unroll
    for (int k = 0; k < 32; ++k) {
        int idx = k * 256 + threadIdx.x;
        int i = base + idx;
        if (i < E) {
            int d = dstash[idx];
            int pos = atomicAdd(&lh[d >> BKT_SHIFT], 1);
            ebuf[pos] = ((d & (BKT_NODES - 1)) << 24) | src[i];
        }
    }
}

// ---- pass 3: per-bucket counting sort -> csr, rowstart, dinv ----
__global__ __launch_bounds__(256) void k_lsort(const int* __restrict__ boff,
                                               const int* __restrict__ ebuf,
                                               int* __restrict__ rowstart,
                                               float* __restrict__ dinv,
                                               int* __restrict__ csr, int n, int NB) {
    __shared__ int off[256];
    __shared__ int cnt[256];
    int b = blockIdx.x;
    int start = boff[b], end = boff[b + 1];
    cnt[threadIdx.x] = 0;
    __syncthreads();
    for (int i = start + threadIdx.x; i < end; i += 256)
        atomicAdd(&cnt[((unsigned)ebuf[i]) >> 24], 1);
    __syncthreads();
    int v = cnt[threadIdx.x];
    off[threadIdx.x] = v;
    __syncthreads();
    for (int o = 1; o < 256; o <<= 1) {
        int t = (threadIdx.x >= o) ? off[threadIdx.x - o] : 0;
        __syncthreads();
        off[threadIdx.x] += t;
        __syncthreads();
    }
    int excl = off[threadIdx.x] - v;
    int node = (b << BKT_SHIFT) + threadIdx.x;
    if (node < n) {
        rowstart[node] = start + excl;
        dinv[node] = rsqrtf((float)v + 1.0f);  // +1 = self-loop
    }
    __syncthreads();
    off[threadIdx.x] = excl;  // reuse as cursor
    __syncthreads();
    for (int i = start + threadIdx.x; i < end; i += 256) {
        int rec = ebuf[i];
        int d = ((unsigned)rec) >> 24;
        int pos = atomicAdd(&off[d], 1);
        csr[start + pos] = rec & 0xFFFFFF;
    }
    if (b == NB - 1 && threadIdx.x == 0) rowstart[n] = end;
}

// ---- hw1 = (x @ W1) * dinv[node]  (8 -> 64) ----
__global__ __launch_bounds__(256) void k_gemm1(const float* __restrict__ x, const float* __restrict__ W1,
                                               const float* __restrict__ dinv, float* __restrict__ hw1, int n) {
    __shared__ float w[512];
    for (int i = threadIdx.x; i < 512; i += 256) w[i] = W1[i];
    __syncthreads();
    int t = blockIdx.x * 256 + threadIdx.x;
    int node = t >> 6, j = t & 63;
    if (node >= n) return;
    float s = 0.f;
#pragma unroll
    for (int k = 0; k < 8; ++k) s += x[node * 8 + k] * w[k * 64 + j];
    hw1[t] = s * dinv[node];
}

// ---- CSR gather-aggregate, 64 feats: g = elu(dv*(sum + hw[self]) + bias) ----
__global__ __launch_bounds__(256) void k_aggr64(const int* __restrict__ rs, const int* __restrict__ csr,
                                                const float* __restrict__ dinv, const float* __restrict__ hw,
                                                const float* __restrict__ bias, float* __restrict__ g, int n) {
    int wid = (blockIdx.x * 256 + threadIdx.x) >> 6;
    if (wid >= n) return;
    int j = threadIdx.x & 63;
    int start = rs[wid], end = rs[wid + 1];
    float a = 0.f;
    int i = start;
    for (; i + 4 <= end; i += 4) {
        int s0 = csr[i], s1 = csr[i + 1], s2 = csr[i + 2], s3 = csr[i + 3];
        a += hw[(size_t)s0 * 64 + j];
        a += hw[(size_t)s1 * 64 + j];
        a += hw[(size_t)s2 * 64 + j];
        a += hw[(size_t)s3 * 64 + j];
    }
    for (; i < end; ++i) a += hw[(size_t)csr[i] * 64 + j];
    float dv = dinv[wid];
    float v = dv * (a + hw[(size_t)wid * 64 + j]) + bias[j];
    g[(size_t)wid * 64 + j] = v > 0.f ? v : expm1f(v);
}

// ---- CSR gather-aggregate, 32 feats (2 edges per wave via halves) ----
__global__ __launch_bounds__(256) void k_aggr32(const int* __restrict__ rs, const int* __restrict__ csr,
                                                const float* __restrict__ dinv, const float* __restrict__ hw,
                                                const float* __restrict__ bias, float* __restrict__ g, int n) {
    int wid = (blockIdx.x * 256 + threadIdx.x) >> 6;
    if (wid >= n) return;
    int j = threadIdx.x & 31;
    int half = (threadIdx.x >> 5) & 1;
    int start = rs[wid], end = rs[wid + 1];
    float a = 0.f;
    int i = start + half;
    for (; i + 2 < end; i += 4) {
        int s0 = csr[i], s1 = csr[i + 2];
        a += hw[(size_t)s0 * 32 + j];
        a += hw[(size_t)s1 * 32 + j];
    }
    for (; i < end; i += 2) a += hw[(size_t)csr[i] * 32 + j];
    a += __shfl_xor(a, 32);
    if (half == 0) {
        float dv = dinv[wid];
        float v = dv * (a + hw[(size_t)wid * 32 + j]) + bias[j];
        g[(size_t)wid * 32 + j] = v > 0.f ? v : expm1f(v);
    }
}

// ---- hw2 = (g1 @ W2) * dinv[node]  (64 -> 32) ----
__global__ __launch_bounds__(256) void k_gemm2(const float* __restrict__ g1, const float* __restrict__ W2,
                                               const float* __restrict__ dinv, float* __restrict__ hw2, int n) {
    __shared__ float w[2048];
    __shared__ float xs[512];
    for (int i = threadIdx.x; i < 2048; i += 256) w[i] = W2[i];
    int nb = blockIdx.x * 8;
    for (int i = threadIdx.x; i < 512; i += 256) {
        int r = i >> 6, c = i & 63;
        int node = nb + r;
        xs[i] = (node < n) ? g1[(size_t)node * 64 + c] : 0.f;
    }
    __syncthreads();
    int node = nb + (threadIdx.x >> 5);
    int j = threadIdx.x & 31;
    if (node >= n) return;
    const float* xr = &xs[(threadIdx.x >> 5) << 6];
    float s = 0.f;
#pragma unroll
    for (int k = 0; k < 64; ++k) s += xr[k] * w[k * 32 + j];
    hw2[(size_t)node * 32 + j] = s * dinv[node];
}

// ---- conv1d(32->16,k=3) + relu + fc(16->22) ----
__global__ __launch_bounds__(256) void k_head(const float* __restrict__ g2, const float* __restrict__ cw,
                                              const float* __restrict__ cb, const float* __restrict__ fw,
                                              const float* __restrict__ fb, float* __restrict__ out,
                                              int nrows) {
    __shared__ float scw[1536], sfw[352], scb[16], sfb[22];
    for (int i = threadIdx.x; i < 1536; i += 256) scw[i] = cw[i];
    for (int i = threadIdx.x; i < 352; i += 256) sfw[i] = fw[i];
    if (threadIdx.x < 16) scb[threadIdx.x] = cb[threadIdx.x];
    if (threadIdx.x < 22) sfb[threadIdx.x] = fb[threadIdx.x];
    __syncthreads();
    int l = blockIdx.x * 256 + threadIdx.x;
    if (l >= nrows) return;
    float xv[96];
    const float4* g4 = reinterpret_cast<const float4*>(g2);
#pragma unroll
    for (int k = 0; k < 3; ++k)
#pragma unroll
        for (int q = 0; q < 8; ++q) {
            float4 v = g4[(size_t)(l + k) * 8 + q];
            xv[k * 32 + q * 4 + 0] = v.x;
            xv[k * 32 + q * 4 + 1] = v.y;
            xv[k * 32 + q * 4 + 2] = v.z;
            xv[k * 32 + q * 4 + 3] = v.w;
        }
    float y[16];
#pragma unroll
    for (int co = 0; co < 16; ++co) {
        float s = scb[co];
#pragma unroll
        for (int ci = 0; ci < 32; ++ci) {
#pragma unroll
            for (int k = 0; k < 3; ++k)
                s += xv[k * 32 + ci] * scw[co * 96 + ci * 3 + k];
        }
        y[co] = s > 0.f ? s : 0.f;
    }
#pragma unroll
    for (int t = 0; t < 22; ++t) {
        float s = sfb[t];
#pragma unroll
        for (int co = 0; co < 16; ++co) s += y[co] * sfw[co * 22 + t];
        out[(size_t)l * 22 + t] = s;
    }
}

extern "C" void kernel_launch(void* const* d_in, const int* in_sizes, int n_in,
                              void* d_out, int out_size, void* d_ws, size_t ws_size,
                              hipStream_t stream) {
    const float* x  = (const float*)d_in[0];
    const int*   ei = (const int*)d_in[1];   // int32 (JAX x64 disabled)
    const float* W1 = (const float*)d_in[2];
    const float* b1 = (const float*)d_in[3];
    const float* W2 = (const float*)d_in[4];
    const float* b2 = (const float*)d_in[5];
    const float* cw = (const float*)d_in[6];
    const float* cb = (const float*)d_in[7];
    const float* fw = (const float*)d_in[8];
    const float* fb = (const float*)d_in[9];
    float* out = (float*)d_out;

    int N = in_sizes[0] / 8;       // 100000
    int E = in_sizes[1] / 2;       // 3200000
    const int* src = ei;
    const int* dst = ei + E;
    int NB = (N + BKT_NODES - 1) >> BKT_SHIFT;  // 391

    auto align256 = [](size_t v) { return (v + 255) & ~(size_t)255; };
    float* ws = (float*)d_ws;
    size_t o = 0;
    int* bcnt = (int*)(ws + o);     o += 512;
    int* boff = (int*)(ws + o);     o += 512;
    int* bcur = (int*)(ws + o);     o += 512;
    int* rowstart = (int*)(ws + o); o += align256(N + 1);
    float* dinv = ws + o;           o += align256(N);
    int* csr = (int*)(ws + o);      o += align256(E);
    float* A = ws + o;              o += (size_t)N * 64;   // hw1, then hw2
    float* B = ws + o;              o += (size_t)N * 64;   // g1, then g2
    int* ebuf = (int*)B;            // ebuf dead before B's first write (aggr64)

    hipMemsetAsync(bcnt, 0, (size_t)NB * sizeof(int), stream);
    k_hist<<<(E + 4095) / 4096, 256, 0, stream>>>(dst, bcnt, E, NB);
    k_bscan<<<1, 512, 0, stream>>>(bcnt, boff, bcur, NB, E);
    k_part<<<(E + 8191) / 8192, 256, 0, stream>>>(src, dst, bcur, ebuf, E, NB);
    k_lsort<<<NB, 256, 0, stream>>>(boff, ebuf, rowstart, dinv, csr, N, NB);

    k_gemm1<<<(int)(((size_t)N * 64 + 255) / 256), 256, 0, stream>>>(x, W1, dinv, A, N);
    k_aggr64<<<(int)(((size_t)N * 64 + 255) / 256), 256, 0, stream>>>(rowstart, csr, dinv, A, b1, B, N);

    k_gemm2<<<(N + 7) / 8, 256, 0, stream>>>(B, W2, dinv, A, N);
    k_aggr32<<<(int)(((size_t)N * 64 + 255) / 256), 256, 0, stream>>>(rowstart, csr, dinv, A, b2, B, N);

    k_head<<<(N - 2 + 255) / 256, 256, 0, stream>>>(B, cw, cb, fw, fb, out, N - 2);
}

// Round 5
// 299.877 us; speedup vs baseline: 7.8348x; 1.2622x over previous
//
#include <hip/hip_runtime.h>
#include <hip/hip_fp16.h>
#include <math.h>

#define BKT_SHIFT 8
#define BKT_NODES 256

// ---- pass 1: per-bucket histogram (int4-vectorized dst read) ----
__global__ __launch_bounds__(256) void k_hist(const int* __restrict__ dst,
                                              int* __restrict__ bcnt, int E, int NB) {
    __shared__ int lh[512];
    for (int i = threadIdx.x; i < NB; i += 256) lh[i] = 0;
    __syncthreads();
    int base = blockIdx.x * 4096;
    if (base + 4096 <= E) {
        const int4* d4 = (const int4*)(dst + base);
#pragma unroll
        for (int k = 0; k < 4; ++k) {
            int4 v = d4[k * 256 + threadIdx.x];
            atomicAdd(&lh[v.x >> BKT_SHIFT], 1);
            atomicAdd(&lh[v.y >> BKT_SHIFT], 1);
            atomicAdd(&lh[v.z >> BKT_SHIFT], 1);
            atomicAdd(&lh[v.w >> BKT_SHIFT], 1);
        }
    } else {
        for (int k = 0; k < 16; ++k) {
            int i = base + k * 256 + threadIdx.x;
            if (i < E) atomicAdd(&lh[dst[i] >> BKT_SHIFT], 1);
        }
    }
    __syncthreads();
    for (int i = threadIdx.x; i < NB; i += 256)
        if (lh[i]) atomicAdd(&bcnt[i], lh[i]);
}

// ---- exclusive scan over NB buckets (single block) ----
__global__ __launch_bounds__(512) void k_bscan(const int* __restrict__ bc,
                                               int* __restrict__ boff,
                                               int* __restrict__ bcur, int NB, int E) {
    __shared__ int s[512];
    __shared__ int carry;
    if (threadIdx.x == 0) carry = 0;
    __syncthreads();
    for (int base = 0; base < NB; base += 512) {
        int i = base + threadIdx.x;
        int v = (i < NB) ? bc[i] : 0;
        s[threadIdx.x] = v;
        __syncthreads();
        for (int off = 1; off < 512; off <<= 1) {
            int t = (threadIdx.x >= off) ? s[threadIdx.x - off] : 0;
            __syncthreads();
            s[threadIdx.x] += t;
            __syncthreads();
        }
        if (i < NB) {
            int ex = carry + s[threadIdx.x] - v;
            boff[i] = ex;
            bcur[i] = ex;
        }
        __syncthreads();
        if (threadIdx.x == 0) carry += s[511];
        __syncthreads();
    }
    if (threadIdx.x == 0) boff[NB] = E;
}

// ---- pass 2: partition edges; record = (d&255)<<24 | src ----
__global__ __launch_bounds__(256) void k_part(const int* __restrict__ src,
                                              const int* __restrict__ dst,
                                              int* __restrict__ bcur,
                                              int* __restrict__ ebuf, int E, int NB) {
    __shared__ int dstash[8192];
    __shared__ int lh[512];
    for (int i = threadIdx.x; i < NB; i += 256) lh[i] = 0;
    __syncthreads();
    int base = blockIdx.x * 8192;
#pragma unroll
    for (int k = 0; k < 32; ++k) {
        int idx = k * 256 + threadIdx.x;
        int i = base + idx;
        if (i < E) {
            int d = dst[i];
            dstash[idx] = d;
            atomicAdd(&lh[d >> BKT_SHIFT], 1);
        }
    }
    __syncthreads();
    for (int t = threadIdx.x; t < NB; t += 256) {
        int c = lh[t];
        lh[t] = c ? atomicAdd(&bcur[t], c) : 0;
    }
    __syncthreads();
#pragma unroll
    for (int k = 0; k < 32; ++k) {
        int idx = k * 256 + threadIdx.x;
        int i = base + idx;
        if (i < E) {
            int d = dstash[idx];
            int pos = atomicAdd(&lh[d >> BKT_SHIFT], 1);
            ebuf[pos] = ((d & (BKT_NODES - 1)) << 24) | src[i];
        }
    }
}

// ---- pass 3: per-bucket counting sort -> csr, rowstart, dinv ----
__global__ __launch_bounds__(256) void k_lsort(const int* __restrict__ boff,
                                               const int* __restrict__ ebuf,
                                               int* __restrict__ rowstart,
                                               float* __restrict__ dinv,
                                               int* __restrict__ csr, int n, int NB) {
    __shared__ int off[256];
    __shared__ int cnt[256];
    int b = blockIdx.x;
    int start = boff[b], end = boff[b + 1];
    cnt[threadIdx.x] = 0;
    __syncthreads();
    for (int i = start + threadIdx.x; i < end; i += 256)
        atomicAdd(&cnt[((unsigned)ebuf[i]) >> 24], 1);
    __syncthreads();
    int v = cnt[threadIdx.x];
    off[threadIdx.x] = v;
    __syncthreads();
    for (int o = 1; o < 256; o <<= 1) {
        int t = (threadIdx.x >= o) ? off[threadIdx.x - o] : 0;
        __syncthreads();
        off[threadIdx.x] += t;
        __syncthreads();
    }
    int excl = off[threadIdx.x] - v;
    int node = (b << BKT_SHIFT) + threadIdx.x;
    if (node < n) {
        rowstart[node] = start + excl;
        dinv[node] = rsqrtf((float)v + 1.0f);  // +1 = self-loop
    }
    __syncthreads();
    off[threadIdx.x] = excl;  // reuse as cursor
    __syncthreads();
    for (int i = start + threadIdx.x; i < end; i += 256) {
        int rec = ebuf[i];
        int d = ((unsigned)rec) >> 24;
        int pos = atomicAdd(&off[d], 1);
        csr[start + pos] = rec & 0xFFFFFF;
    }
    if (b == NB - 1 && threadIdx.x == 0) rowstart[n] = end;
}

// ---- hw1 = fp16((x @ W1) * dinv)  (8 -> 64) ----
__global__ __launch_bounds__(256) void k_gemm1(const float* __restrict__ x, const float* __restrict__ W1,
                                               const float* __restrict__ dinv, __half* __restrict__ hw1, int n) {
    __shared__ float w[512];
    for (int i = threadIdx.x; i < 512; i += 256) w[i] = W1[i];
    __syncthreads();
    int t = blockIdx.x * 256 + threadIdx.x;
    int node = t >> 6, j = t & 63;
    if (node >= n) return;
    float s = 0.f;
#pragma unroll
    for (int k = 0; k < 8; ++k) s += x[node * 8 + k] * w[k * 64 + j];
    hw1[t] = __float2half_rn(s * dinv[node]);
}

// ---- CSR gather-aggregate, 64 feats fp16: wave = 2 halves x 32 lanes x half2 ----
__global__ __launch_bounds__(256) void k_aggr64h(const int* __restrict__ rs, const int* __restrict__ csr,
                                                 const float* __restrict__ dinv, const __half* __restrict__ hw,
                                                 const float* __restrict__ bias, float* __restrict__ g, int n) {
    int wid = (blockIdx.x * 256 + threadIdx.x) >> 6;
    if (wid >= n) return;
    int lane = threadIdx.x & 63;
    int half = lane >> 5;        // 0/1 : which edge subset
    int j = lane & 31;           // feature pair index (feats 2j, 2j+1)
    int start = rs[wid], end = rs[wid + 1];
    const __half2* hp = (const __half2*)hw;
    float ax = 0.f, ay = 0.f;
    int i = start + half;
    for (; i + 6 < end; i += 8) {
        int s0 = csr[i], s1 = csr[i + 2], s2 = csr[i + 4], s3 = csr[i + 6];
        float2 f0 = __half22float2(hp[((size_t)s0 << 5) + j]);
        float2 f1 = __half22float2(hp[((size_t)s1 << 5) + j]);
        float2 f2 = __half22float2(hp[((size_t)s2 << 5) + j]);
        float2 f3 = __half22float2(hp[((size_t)s3 << 5) + j]);
        ax += f0.x + f1.x + f2.x + f3.x;
        ay += f0.y + f1.y + f2.y + f3.y;
    }
    for (; i < end; i += 2) {
        float2 f = __half22float2(hp[((size_t)csr[i] << 5) + j]);
        ax += f.x; ay += f.y;
    }
    ax += __shfl_xor(ax, 32);
    ay += __shfl_xor(ay, 32);
    if (half == 0) {
        float dv = dinv[wid];
        float2 fs = __half22float2(hp[((size_t)wid << 5) + j]);
        float2 bb = ((const float2*)bias)[j];
        float vx = dv * (ax + fs.x) + bb.x;
        float vy = dv * (ay + fs.y) + bb.y;
        float2 r;
        r.x = vx > 0.f ? vx : expm1f(vx);
        r.y = vy > 0.f ? vy : expm1f(vy);
        ((float2*)(g + ((size_t)wid << 6)))[j] = r;
    }
}

// ---- CSR gather-aggregate, 32 feats fp16: wave = 4 quarters x 16 lanes x half2 ----
__global__ __launch_bounds__(256) void k_aggr32h(const int* __restrict__ rs, const int* __restrict__ csr,
                                                 const float* __restrict__ dinv, const __half* __restrict__ hw,
                                                 const float* __restrict__ bias, float* __restrict__ g, int n) {
    int wid = (blockIdx.x * 256 + threadIdx.x) >> 6;
    if (wid >= n) return;
    int lane = threadIdx.x & 63;
    int q = lane >> 4;           // 0..3 : edge subset
    int j = lane & 15;           // feature pair index (feats 2j, 2j+1)
    int start = rs[wid], end = rs[wid + 1];
    const __half2* hp = (const __half2*)hw;
    float ax = 0.f, ay = 0.f;
    int i = start + q;
    for (; i + 4 < end; i += 8) {
        int s0 = csr[i], s1 = csr[i + 4];
        float2 f0 = __half22float2(hp[((size_t)s0 << 4) + j]);
        float2 f1 = __half22float2(hp[((size_t)s1 << 4) + j]);
        ax += f0.x + f1.x;
        ay += f0.y + f1.y;
    }
    for (; i < end; i += 4) {
        float2 f = __half22float2(hp[((size_t)csr[i] << 4) + j]);
        ax += f.x; ay += f.y;
    }
    ax += __shfl_xor(ax, 16);
    ay += __shfl_xor(ay, 16);
    ax += __shfl_xor(ax, 32);
    ay += __shfl_xor(ay, 32);
    if (q == 0) {
        float dv = dinv[wid];
        float2 fs = __half22float2(hp[((size_t)wid << 4) + j]);
        float2 bb = ((const float2*)bias)[j];
        float vx = dv * (ax + fs.x) + bb.x;
        float vy = dv * (ay + fs.y) + bb.y;
        float2 r;
        r.x = vx > 0.f ? vx : expm1f(vx);
        r.y = vy > 0.f ? vy : expm1f(vy);
        ((float2*)(g + ((size_t)wid << 5)))[j] = r;
    }
}

// ---- hw2 = fp16((g1 @ W2) * dinv)  (64 -> 32) ----
__global__ __launch_bounds__(256) void k_gemm2(const float* __restrict__ g1, const float* __restrict__ W2,
                                               const float* __restrict__ dinv, __half* __restrict__ hw2, int n) {
    __shared__ float w[2048];
    __shared__ float xs[512];
    for (int i = threadIdx.x; i < 2048; i += 256) w[i] = W2[i];
    int nb = blockIdx.x * 8;
    for (int i = threadIdx.x; i < 512; i += 256) {
        int r = i >> 6, c = i & 63;
        int node = nb + r;
        xs[i] = (node < n) ? g1[(size_t)node * 64 + c] : 0.f;
    }
    __syncthreads();
    int node = nb + (threadIdx.x >> 5);
    int j = threadIdx.x & 31;
    if (node >= n) return;
    const float* xr = &xs[(threadIdx.x >> 5) << 6];
    float s = 0.f;
#pragma unroll
    for (int k = 0; k < 64; ++k) s += xr[k] * w[k * 32 + j];
    hw2[(size_t)node * 32 + j] = __float2half_rn(s * dinv[node]);
}

// ---- conv1d(32->16,k=3) + relu + fc(16->22) ----
__global__ __launch_bounds__(256) void k_head(const float* __restrict__ g2, const float* __restrict__ cw,
                                              const float* __restrict__ cb, const float* __restrict__ fw,
                                              const float* __restrict__ fb, float* __restrict__ out,
                                              int nrows) {
    __shared__ float scw[1536], sfw[352], scb[16], sfb[22];
    for (int i = threadIdx.x; i < 1536; i += 256) scw[i] = cw[i];
    for (int i = threadIdx.x; i < 352; i += 256) sfw[i] = fw[i];
    if (threadIdx.x < 16) scb[threadIdx.x] = cb[threadIdx.x];
    if (threadIdx.x < 22) sfb[threadIdx.x] = fb[threadIdx.x];
    __syncthreads();
    int l = blockIdx.x * 256 + threadIdx.x;
    if (l >= nrows) return;
    float xv[96];
    const float4* g4 = reinterpret_cast<const float4*>(g2);
#pragma unroll
    for (int k = 0; k < 3; ++k)
#pragma unroll
        for (int q = 0; q < 8; ++q) {
            float4 v = g4[(size_t)(l + k) * 8 + q];
            xv[k * 32 + q * 4 + 0] = v.x;
            xv[k * 32 + q * 4 + 1] = v.y;
            xv[k * 32 + q * 4 + 2] = v.z;
            xv[k * 32 + q * 4 + 3] = v.w;
        }
    float y[16];
#pragma unroll
    for (int co = 0; co < 16; ++co) {
        float s = scb[co];
#pragma unroll
        for (int ci = 0; ci < 32; ++ci) {
#pragma unroll
            for (int k = 0; k < 3; ++k)
                s += xv[k * 32 + ci] * scw[co * 96 + ci * 3 + k];
        }
        y[co] = s > 0.f ? s : 0.f;
    }
#pragma unroll
    for (int t = 0; t < 22; ++t) {
        float s = sfb[t];
#pragma unroll
        for (int co = 0; co < 16; ++co) s += y[co] * sfw[co * 22 + t];
        out[(size_t)l * 22 + t] = s;
    }
}

extern "C" void kernel_launch(void* const* d_in, const int* in_sizes, int n_in,
                              void* d_out, int out_size, void* d_ws, size_t ws_size,
                              hipStream_t stream) {
    const float* x  = (const float*)d_in[0];
    const int*   ei = (const int*)d_in[1];   // int32 (JAX x64 disabled)
    const float* W1 = (const float*)d_in[2];
    const float* b1 = (const float*)d_in[3];
    const float* W2 = (const float*)d_in[4];
    const float* b2 = (const float*)d_in[5];
    const float* cw = (const float*)d_in[6];
    const float* cb = (const float*)d_in[7];
    const float* fw = (const float*)d_in[8];
    const float* fb = (const float*)d_in[9];
    float* out = (float*)d_out;

    int N = in_sizes[0] / 8;       // 100000
    int E = in_sizes[1] / 2;       // 3200000
    const int* src = ei;
    const int* dst = ei + E;
    int NB = (N + BKT_NODES - 1) >> BKT_SHIFT;  // 391

    auto alignB = [](size_t v) { return (v + 1023) & ~(size_t)1023; };
    char* wsb = (char*)d_ws;
    size_t o = 0;
    int* bcnt = (int*)(wsb + o);     o += 2048;
    int* boff = (int*)(wsb + o);     o += 2048;
    int* bcur = (int*)(wsb + o);     o += 2048;
    int* rowstart = (int*)(wsb + o); o += alignB((size_t)(N + 1) * 4);
    float* dinv = (float*)(wsb + o); o += alignB((size_t)N * 4);
    int* csr = (int*)(wsb + o);      o += alignB((size_t)E * 4);
    __half* hwA = (__half*)(wsb + o); o += alignB((size_t)N * 64 * 2);  // hw1, then hw2
    float* B = (float*)(wsb + o);    o += (size_t)N * 64 * 4;           // g1, then g2
    int* ebuf = (int*)B;             // dead before B's first write

    hipMemsetAsync(bcnt, 0, (size_t)NB * sizeof(int), stream);
    k_hist<<<(E + 4095) / 4096, 256, 0, stream>>>(dst, bcnt, E, NB);
    k_bscan<<<1, 512, 0, stream>>>(bcnt, boff, bcur, NB, E);
    k_part<<<(E + 8191) / 8192, 256, 0, stream>>>(src, dst, bcur, ebuf, E, NB);
    k_lsort<<<NB, 256, 0, stream>>>(boff, ebuf, rowstart, dinv, csr, N, NB);

    k_gemm1<<<(int)(((size_t)N * 64 + 255) / 256), 256, 0, stream>>>(x, W1, dinv, hwA, N);
    k_aggr64h<<<(int)(((size_t)N * 64 + 255) / 256), 256, 0, stream>>>(rowstart, csr, dinv, hwA, b1, B, N);

    k_gemm2<<<(N + 7) / 8, 256, 0, stream>>>(B, W2, dinv, hwA, N);
    k_aggr32h<<<(int)(((size_t)N * 64 + 255) / 256), 256, 0, stream>>>(rowstart, csr, dinv, hwA, b2, B, N);

    k_head<<<(N - 2 + 255) / 256, 256, 0, stream>>>(B, cw, cb, fw, fb, out, N - 2);
}

// Round 6
// 243.688 us; speedup vs baseline: 9.6414x; 1.2306x over previous
//
#include <hip/hip_runtime.h>
#include <hip/hip_fp16.h>
#include <math.h>

#define BKT_SHIFT 8
#define BKT_NODES 256

// ---- pass 1: per-bucket histogram (int4-vectorized dst read) ----
__global__ __launch_bounds__(256) void k_hist(const int* __restrict__ dst,
                                              int* __restrict__ bcnt, int E, int NB) {
    __shared__ int lh[512];
    for (int i = threadIdx.x; i < NB; i += 256) lh[i] = 0;
    __syncthreads();
    int base = blockIdx.x * 4096;
    if (base + 4096 <= E) {
        const int4* d4 = (const int4*)(dst + base);
#pragma unroll
        for (int k = 0; k < 4; ++k) {
            int4 v = d4[k * 256 + threadIdx.x];
            atomicAdd(&lh[v.x >> BKT_SHIFT], 1);
            atomicAdd(&lh[v.y >> BKT_SHIFT], 1);
            atomicAdd(&lh[v.z >> BKT_SHIFT], 1);
            atomicAdd(&lh[v.w >> BKT_SHIFT], 1);
        }
    } else {
        for (int k = 0; k < 16; ++k) {
            int i = base + k * 256 + threadIdx.x;
            if (i < E) atomicAdd(&lh[dst[i] >> BKT_SHIFT], 1);
        }
    }
    __syncthreads();
    for (int i = threadIdx.x; i < NB; i += 256)
        if (lh[i]) atomicAdd(&bcnt[i], lh[i]);
}

// ---- exclusive scan over NB buckets (single block) ----
__global__ __launch_bounds__(512) void k_bscan(const int* __restrict__ bc,
                                               int* __restrict__ boff,
                                               int* __restrict__ bcur, int NB, int E) {
    __shared__ int s[512];
    __shared__ int carry;
    if (threadIdx.x == 0) carry = 0;
    __syncthreads();
    for (int base = 0; base < NB; base += 512) {
        int i = base + threadIdx.x;
        int v = (i < NB) ? bc[i] : 0;
        s[threadIdx.x] = v;
        __syncthreads();
        for (int off = 1; off < 512; off <<= 1) {
            int t = (threadIdx.x >= off) ? s[threadIdx.x - off] : 0;
            __syncthreads();
            s[threadIdx.x] += t;
            __syncthreads();
        }
        if (i < NB) {
            int ex = carry + s[threadIdx.x] - v;
            boff[i] = ex;
            bcur[i] = ex;
        }
        __syncthreads();
        if (threadIdx.x == 0) carry += s[511];
        __syncthreads();
    }
    if (threadIdx.x == 0) boff[NB] = E;
}

// ---- pass 2: partition edges; record = (d&255)<<24 | src ----
__global__ __launch_bounds__(256) void k_part(const int* __restrict__ src,
                                              const int* __restrict__ dst,
                                              int* __restrict__ bcur,
                                              int* __restrict__ ebuf, int E, int NB) {
    __shared__ int dstash[8192];
    __shared__ int lh[512];
    for (int i = threadIdx.x; i < NB; i += 256) lh[i] = 0;
    __syncthreads();
    int base = blockIdx.x * 8192;
#pragma unroll
    for (int k = 0; k < 32; ++k) {
        int idx = k * 256 + threadIdx.x;
        int i = base + idx;
        if (i < E) {
            int d = dst[i];
            dstash[idx] = d;
            atomicAdd(&lh[d >> BKT_SHIFT], 1);
        }
    }
    __syncthreads();
    for (int t = threadIdx.x; t < NB; t += 256) {
        int c = lh[t];
        lh[t] = c ? atomicAdd(&bcur[t], c) : 0;
    }
    __syncthreads();
#pragma unroll
    for (int k = 0; k < 32; ++k) {
        int idx = k * 256 + threadIdx.x;
        int i = base + idx;
        if (i < E) {
            int d = dstash[idx];
            int pos = atomicAdd(&lh[d >> BKT_SHIFT], 1);
            ebuf[pos] = ((d & (BKT_NODES - 1)) << 24) | src[i];
        }
    }
}

// ---- pass 3: per-bucket counting sort -> csr, rowstart, dinv ----
__global__ __launch_bounds__(256) void k_lsort(const int* __restrict__ boff,
                                               const int* __restrict__ ebuf,
                                               int* __restrict__ rowstart,
                                               float* __restrict__ dinv,
                                               int* __restrict__ csr, int n, int NB) {
    __shared__ int off[256];
    __shared__ int cnt[256];
    int b = blockIdx.x;
    int start = boff[b], end = boff[b + 1];
    cnt[threadIdx.x] = 0;
    __syncthreads();
    for (int i = start + threadIdx.x; i < end; i += 256)
        atomicAdd(&cnt[((unsigned)ebuf[i]) >> 24], 1);
    __syncthreads();
    int v = cnt[threadIdx.x];
    off[threadIdx.x] = v;
    __syncthreads();
    for (int o = 1; o < 256; o <<= 1) {
        int t = (threadIdx.x >= o) ? off[threadIdx.x - o] : 0;
        __syncthreads();
        off[threadIdx.x] += t;
        __syncthreads();
    }
    int excl = off[threadIdx.x] - v;
    int node = (b << BKT_SHIFT) + threadIdx.x;
    if (node < n) {
        rowstart[node] = start + excl;
        dinv[node] = rsqrtf((float)v + 1.0f);  // +1 = self-loop
    }
    __syncthreads();
    off[threadIdx.x] = excl;  // reuse as cursor
    __syncthreads();
    for (int i = start + threadIdx.x; i < end; i += 256) {
        int rec = ebuf[i];
        int d = ((unsigned)rec) >> 24;
        int pos = atomicAdd(&off[d], 1);
        csr[start + pos] = rec & 0xFFFFFF;
    }
    if (b == NB - 1 && threadIdx.x == 0) rowstart[n] = end;
}

// ---- hx = fp16(x * dinv), [N][8]; thread handles 2 feats ----
__global__ __launch_bounds__(256) void k_hx(const float* __restrict__ x,
                                            const float* __restrict__ dinv,
                                            __half2* __restrict__ hx, int n4) {
    int t = blockIdx.x * 256 + threadIdx.x;
    if (t >= n4) return;
    float2 v = ((const float2*)x)[t];
    float dv = dinv[t >> 2];
    hx[t] = __floats2half2_rn(v.x * dv, v.y * dv);
}

// ---- fused layer-1: aggregate hx (8 feats) over edges+self, then @W1+bias+ELU ----
// wave per node: 16 edge-subsets x 4 lanes(half2)
__global__ __launch_bounds__(256) void k_agg1f(const int* __restrict__ rs, const int* __restrict__ csr,
                                               const float* __restrict__ dinv, const __half2* __restrict__ hx,
                                               const float* __restrict__ W1, const float* __restrict__ bias,
                                               float* __restrict__ g, int n) {
    __shared__ float w[512];
    for (int i = threadIdx.x; i < 512; i += 256) w[i] = W1[i];
    __syncthreads();
    int wid = (blockIdx.x * 256 + threadIdx.x) >> 6;
    if (wid >= n) return;
    int lane = threadIdx.x & 63;
    int sub = lane >> 2;        // 0..15 edge subset
    int jp = lane & 3;          // half2 index (feats 2jp, 2jp+1)
    int start = rs[wid], end = rs[wid + 1];
    float ax = 0.f, ay = 0.f;
    int i = start + sub;
    for (; i + 16 < end; i += 32) {
        int s0 = csr[i], s1 = csr[i + 16];
        float2 f0 = __half22float2(hx[((size_t)s0 << 2) + jp]);
        float2 f1 = __half22float2(hx[((size_t)s1 << 2) + jp]);
        ax += f0.x + f1.x;
        ay += f0.y + f1.y;
    }
    for (; i < end; i += 16) {
        float2 f = __half22float2(hx[((size_t)csr[i] << 2) + jp]);
        ax += f.x; ay += f.y;
    }
    if (sub == 0) {  // self-loop row
        float2 f = __half22float2(hx[((size_t)wid << 2) + jp]);
        ax += f.x; ay += f.y;
    }
#pragma unroll
    for (int m = 4; m < 64; m <<= 1) {
        ax += __shfl_xor(ax, m);
        ay += __shfl_xor(ay, m);
    }
    // every lane now holds agg for feats (2jp, 2jp+1); broadcast all 8 and apply W1
    float dv = dinv[wid];
    float s = 0.f;
#pragma unroll
    for (int kp = 0; kp < 4; ++kp) {
        float a = __shfl(ax, kp);
        float b = __shfl(ay, kp);
        s += a * w[(2 * kp) * 64 + lane] + b * w[(2 * kp + 1) * 64 + lane];
    }
    float v = dv * s + bias[lane];
    g[(size_t)wid * 64 + lane] = v > 0.f ? v : expm1f(v);
}

// ---- CSR gather-aggregate, 32 feats fp16: wave = 4 quarters x 16 lanes x half2 ----
__global__ __launch_bounds__(256) void k_aggr32h(const int* __restrict__ rs, const int* __restrict__ csr,
                                                 const float* __restrict__ dinv, const __half* __restrict__ hw,
                                                 const float* __restrict__ bias, float* __restrict__ g, int n) {
    int wid = (blockIdx.x * 256 + threadIdx.x) >> 6;
    if (wid >= n) return;
    int lane = threadIdx.x & 63;
    int q = lane >> 4;           // 0..3 : edge subset
    int j = lane & 15;           // feature pair index (feats 2j, 2j+1)
    int start = rs[wid], end = rs[wid + 1];
    const __half2* hp = (const __half2*)hw;
    float ax = 0.f, ay = 0.f;
    int i = start + q;
    for (; i + 12 < end; i += 16) {
        int s0 = csr[i], s1 = csr[i + 4], s2 = csr[i + 8], s3 = csr[i + 12];
        float2 f0 = __half22float2(hp[((size_t)s0 << 4) + j]);
        float2 f1 = __half22float2(hp[((size_t)s1 << 4) + j]);
        float2 f2 = __half22float2(hp[((size_t)s2 << 4) + j]);
        float2 f3 = __half22float2(hp[((size_t)s3 << 4) + j]);
        ax += f0.x + f1.x + f2.x + f3.x;
        ay += f0.y + f1.y + f2.y + f3.y;
    }
    for (; i < end; i += 4) {
        float2 f = __half22float2(hp[((size_t)csr[i] << 4) + j]);
        ax += f.x; ay += f.y;
    }
    ax += __shfl_xor(ax, 16);
    ay += __shfl_xor(ay, 16);
    ax += __shfl_xor(ax, 32);
    ay += __shfl_xor(ay, 32);
    if (q == 0) {
        float dv = dinv[wid];
        float2 fs = __half22float2(hp[((size_t)wid << 4) + j]);
        float2 bb = ((const float2*)bias)[j];
        float vx = dv * (ax + fs.x) + bb.x;
        float vy = dv * (ay + fs.y) + bb.y;
        float2 r;
        r.x = vx > 0.f ? vx : expm1f(vx);
        r.y = vy > 0.f ? vy : expm1f(vy);
        ((float2*)(g + ((size_t)wid << 5)))[j] = r;
    }
}

// ---- hw2 = fp16((g1 @ W2) * dinv)  (64 -> 32) ----
__global__ __launch_bounds__(256) void k_gemm2(const float* __restrict__ g1, const float* __restrict__ W2,
                                               const float* __restrict__ dinv, __half* __restrict__ hw2, int n) {
    __shared__ float w[2048];
    __shared__ float xs[512];
    for (int i = threadIdx.x; i < 2048; i += 256) w[i] = W2[i];
    int nb = blockIdx.x * 8;
    for (int i = threadIdx.x; i < 512; i += 256) {
        int r = i >> 6, c = i & 63;
        int node = nb + r;
        xs[i] = (node < n) ? g1[(size_t)node * 64 + c] : 0.f;
    }
    __syncthreads();
    int node = nb + (threadIdx.x >> 5);
    int j = threadIdx.x & 31;
    if (node >= n) return;
    const float* xr = &xs[(threadIdx.x >> 5) << 6];
    float s = 0.f;
#pragma unroll
    for (int k = 0; k < 64; ++k) s += xr[k] * w[k * 32 + j];
    hw2[(size_t)node * 32 + j] = __float2half_rn(s * dinv[node]);
}

// ---- conv1d(32->16,k=3) + relu + fc(16->22) ----
__global__ __launch_bounds__(256) void k_head(const float* __restrict__ g2, const float* __restrict__ cw,
                                              const float* __restrict__ cb, const float* __restrict__ fw,
                                              const float* __restrict__ fb, float* __restrict__ out,
                                              int nrows) {
    __shared__ float scw[1536], sfw[352], scb[16], sfb[22];
    for (int i = threadIdx.x; i < 1536; i += 256) scw[i] = cw[i];
    for (int i = threadIdx.x; i < 352; i += 256) sfw[i] = fw[i];
    if (threadIdx.x < 16) scb[threadIdx.x] = cb[threadIdx.x];
    if (threadIdx.x < 22) sfb[threadIdx.x] = fb[threadIdx.x];
    __syncthreads();
    int l = blockIdx.x * 256 + threadIdx.x;
    if (l >= nrows) return;
    float xv[96];
    const float4* g4 = reinterpret_cast<const float4*>(g2);
#pragma unroll
    for (int k = 0; k < 3; ++k)
#pragma unroll
        for (int q = 0; q < 8; ++q) {
            float4 v = g4[(size_t)(l + k) * 8 + q];
            xv[k * 32 + q * 4 + 0] = v.x;
            xv[k * 32 + q * 4 + 1] = v.y;
            xv[k * 32 + q * 4 + 2] = v.z;
            xv[k * 32 + q * 4 + 3] = v.w;
        }
    float y[16];
#pragma unroll
    for (int co = 0; co < 16; ++co) {
        float s = scb[co];
#pragma unroll
        for (int ci = 0; ci < 32; ++ci) {
#pragma unroll
            for (int k = 0; k < 3; ++k)
                s += xv[k * 32 + ci] * scw[co * 96 + ci * 3 + k];
        }
        y[co] = s > 0.f ? s : 0.f;
    }
#pragma unroll
    for (int t = 0; t < 22; ++t) {
        float s = sfb[t];
#pragma unroll
        for (int co = 0; co < 16; ++co) s += y[co] * sfw[co * 22 + t];
        out[(size_t)l * 22 + t] = s;
    }
}

extern "C" void kernel_launch(void* const* d_in, const int* in_sizes, int n_in,
                              void* d_out, int out_size, void* d_ws, size_t ws_size,
                              hipStream_t stream) {
    const float* x  = (const float*)d_in[0];
    const int*   ei = (const int*)d_in[1];   // int32 (JAX x64 disabled)
    const float* W1 = (const float*)d_in[2];
    const float* b1 = (const float*)d_in[3];
    const float* W2 = (const float*)d_in[4];
    const float* b2 = (const float*)d_in[5];
    const float* cw = (const float*)d_in[6];
    const float* cb = (const float*)d_in[7];
    const float* fw = (const float*)d_in[8];
    const float* fb = (const float*)d_in[9];
    float* out = (float*)d_out;

    int N = in_sizes[0] / 8;       // 100000
    int E = in_sizes[1] / 2;       // 3200000
    const int* src = ei;
    const int* dst = ei + E;
    int NB = (N + BKT_NODES - 1) >> BKT_SHIFT;  // 391

    auto alignB = [](size_t v) { return (v + 1023) & ~(size_t)1023; };
    char* wsb = (char*)d_ws;
    size_t o = 0;
    int* bcnt = (int*)(wsb + o);     o += 2048;
    int* boff = (int*)(wsb + o);     o += 2048;
    int* bcur = (int*)(wsb + o);     o += 2048;
    int* rowstart = (int*)(wsb + o); o += alignB((size_t)(N + 1) * 4);
    float* dinv = (float*)(wsb + o); o += alignB((size_t)N * 4);
    int* csr = (int*)(wsb + o);      o += alignB((size_t)E * 4);
    __half2* hx = (__half2*)(wsb + o); o += alignB((size_t)N * 8 * 2);   // [N][8] fp16
    __half* hw2 = (__half*)(wsb + o);  o += alignB((size_t)N * 32 * 2);  // [N][32] fp16
    float* B = (float*)(wsb + o);    o += (size_t)N * 64 * 4;            // g1, then g2
    int* ebuf = (int*)B;             // dead before B's first write

    hipMemsetAsync(bcnt, 0, (size_t)NB * sizeof(int), stream);
    k_hist<<<(E + 4095) / 4096, 256, 0, stream>>>(dst, bcnt, E, NB);
    k_bscan<<<1, 512, 0, stream>>>(bcnt, boff, bcur, NB, E);
    k_part<<<(E + 8191) / 8192, 256, 0, stream>>>(src, dst, bcur, ebuf, E, NB);
    k_lsort<<<NB, 256, 0, stream>>>(boff, ebuf, rowstart, dinv, csr, N, NB);

    k_hx<<<(N * 4 + 255) / 256, 256, 0, stream>>>(x, dinv, hx, N * 4);
    k_agg1f<<<(int)(((size_t)N * 64 + 255) / 256), 256, 0, stream>>>(rowstart, csr, dinv, hx, W1, b1, B, N);

    k_gemm2<<<(N + 7) / 8, 256, 0, stream>>>(B, W2, dinv, hw2, N);
    k_aggr32h<<<(int)(((size_t)N * 64 + 255) / 256), 256, 0, stream>>>(rowstart, csr, dinv, hw2, b2, B, N);

    k_head<<<(N - 2 + 255) / 256, 256, 0, stream>>>(B, cw, cb, fw, fb, out, N - 2);
}